// Round 23
// baseline (76.788 us; speedup 1.0000x reference)
//
#include <hip/hip_runtime.h>
#include <float.h>
#include <limits.h>

#define BATCH 32
#define C_IN 16
#define C_OUT 32
#define NTOK 2048
#define KNN 3
#define WPB 4                 // waves per scan block
#define NPLANE 16             // key planes: quad*4 + j

using f32x4v = __attribute__((ext_vector_type(4))) float;
using bf16x8 = __attribute__((ext_vector_type(8))) short;

__device__ __forceinline__ unsigned short f2bf(float f) {
    unsigned u = __float_as_uint(f);
    unsigned r = u + 0x7fffu + ((u >> 16) & 1u);   // RNE
    return (unsigned short)(r >> 16);
}
__device__ __forceinline__ float bf2f(unsigned short h) {
    return __uint_as_float(((unsigned)h) << 16);
}
__device__ __forceinline__ unsigned umin2(unsigned a, unsigned b) { return a < b ? a : b; }
__device__ __forceinline__ unsigned med3u(unsigned a, unsigned b, unsigned c) {
    unsigned d;
    asm("v_med3_u32 %0, %1, %2, %3" : "=v"(d) : "v"(a), "v"(b), "v"(c));
    return d;
}

// Kernel 1: per (b,n): sq (exact ref recipe), xTf fp32 column, Am bf16 hi/lo split.
// Am layout: FRAGMENT-TILE-INTERLEAVED (R13): uint4 index nt*64 + q*16 + col holds
// k-chunk q (0,1 = hi; 2,3 = lo) of row nt*16+col.
__global__ void __launch_bounds__(256) prep_kernel(
    const float* __restrict__ x, float* __restrict__ xTf,
    float* __restrict__ sqf, uint4* __restrict__ Am)
{
    const int n = blockIdx.x * 256 + threadIdx.x;
    const int b = blockIdx.y;
    const float* xb = x + (size_t)b * C_IN * NTOK;

    float v[C_IN];
#pragma unroll
    for (int c = 0; c < C_IN; ++c) v[c] = xb[(size_t)c * NTOK + n];

    float acc = 0.0f;
#pragma unroll
    for (int c = 0; c < C_IN; ++c) acc = __fadd_rn(acc, __fmul_rn(v[c], v[c]));
    sqf[(size_t)b * NTOK + n] = acc;

    float4* dst = (float4*)(xTf + ((size_t)b * NTOK + n) * C_IN);
#pragma unroll
    for (int j = 0; j < 4; ++j)
        dst[j] = make_float4(v[4*j+0], v[4*j+1], v[4*j+2], v[4*j+3]);

    unsigned hw[8], lw[8];
#pragma unroll
    for (int j = 0; j < 8; ++j) {
        const unsigned short h0 = f2bf(v[2*j]),   h1 = f2bf(v[2*j+1]);
        const unsigned short l0 = f2bf(v[2*j]   - bf2f(h0));
        const unsigned short l1 = f2bf(v[2*j+1] - bf2f(h1));
        hw[j] = (unsigned)h0 | ((unsigned)h1 << 16);
        lw[j] = (unsigned)l0 | ((unsigned)l1 << 16);
    }
    uint4* amb = Am + (size_t)b * NTOK * 4;
    const int nt  = n >> 4;
    const int col = n & 15;
    amb[nt*64 + 0*16 + col] = make_uint4(hw[0], hw[1], hw[2], hw[3]);  // hi chunk0
    amb[nt*64 + 1*16 + col] = make_uint4(hw[4], hw[5], hw[6], hw[7]);  // hi chunk1
    amb[nt*64 + 2*16 + col] = make_uint4(lw[0], lw[1], lw[2], lw[3]);  // lo chunk0
    amb[nt*64 + 3*16 + col] = make_uint4(lw[4], lw[5], lw[6], lw[7]);  // lo chunk1
}

// Kernel 2: LEAN scan, ZH=1, TWO n-tiles per wave. The same Af load feeds both
// tiles' MFMAs (A-traffic per unit work halves) and the two tiles' key/insert
// chains are independent -> 2x ILP in the stall shadow. 512 blocks (8 waves/CU
// demanded, under the ~16/CU cap). Candidate geometry per n unchanged (4 quads
// x top-4 over disjoint 512-m subsets) -> rescore/merge identical.
__global__ void __launch_bounds__(256) knn_scan_kernel(
    const uint4* __restrict__ Am, const float* __restrict__ sqf,
    unsigned* __restrict__ keyws)
{
    const int tid  = threadIdx.x;
    const int w    = tid >> 6;
    const int l    = tid & 63;
    const int col  = l & 15;
    const int quad = l >> 4;

    // decode swizzled block coords: wgid = (b%8) + 8*((b/8)*16 + ntp)
    const int wg   = blockIdx.x;        // 0..511
    const int b_lo = wg & 7;
    const int t2   = wg >> 3;           // 0..63
    const int b_hi = t2 >> 4;           // 0..3
    const int ntp  = t2 & 15;           // 0..15
    const int b    = b_lo + (b_hi << 3);
    const int nt0  = (ntp * WPB + w) * 2;   // tile pair
    const int nt1  = nt0 + 1;

    const int n0 = nt0 * 16 + col;
    const int n1 = nt1 * 16 + col;

    const uint4* amb = Am + (size_t)b * NTOK * 4;
    const float* sqb = sqf + (size_t)b * NTOK;

    // B-frags for both tiles (R13 interleaved layout)
    const uint4 bh40 = amb[(size_t)nt0*64 + ((quad & 1) * 16) + col];
    const uint4 bl40 = amb[(size_t)nt0*64 + ((2 + (quad & 1)) * 16) + col];
    const uint4 bh41 = amb[(size_t)nt1*64 + ((quad & 1) * 16) + col];
    const uint4 bl41 = amb[(size_t)nt1*64 + ((2 + (quad & 1)) * 16) + col];
    const bf16x8 Bhi0 = *(const bf16x8*)&bh40;
    const bf16x8 Blo0 = *(const bf16x8*)&bl40;
    const bf16x8 Bhi1 = *(const bf16x8*)&bh41;
    const bf16x8 Blo1 = *(const bf16x8*)&bl41;

    // ranking biases (R14): strictly positive biased keys, uint-monotone
    const float bias0 = sqb[n0] + 4.0f;
    const float bias1 = sqb[n1] + 4.0f;

    unsigned a0 = ~0u, a1 = ~0u, a2 = ~0u, a3 = ~0u;   // tile 0 top-4
    unsigned c0 = ~0u, c1 = ~0u, c2 = ~0u, c3 = ~0u;   // tile 1 top-4
    const int moff = quad * 4;

#pragma unroll 2
    for (int t = 0; t < NTOK / 16; ++t) {
        // A-frag: one coalesced load serves BOTH tiles
        const uint4 af4 = amb[(size_t)t * 64 + l];
        const bf16x8 Af = *(const bf16x8*)&af4;
        const float4 sq4 = *(const float4*)(sqb + t * 16 + moff);

        f32x4v acc0 = {0.0f, 0.0f, 0.0f, 0.0f};
        f32x4v acc1 = {0.0f, 0.0f, 0.0f, 0.0f};
        acc0 = __builtin_amdgcn_mfma_f32_16x16x32_bf16(Af, Bhi0, acc0, 0, 0, 0);
        acc1 = __builtin_amdgcn_mfma_f32_16x16x32_bf16(Af, Bhi1, acc1, 0, 0, 0);
        acc0 = __builtin_amdgcn_mfma_f32_16x16x32_bf16(Af, Blo0, acc0, 0, 0, 0);
        acc1 = __builtin_amdgcn_mfma_f32_16x16x32_bf16(Af, Blo1, acc1, 0, 0, 0);

        const int mb = t * 16 + moff;
        const float sqa[4] = { sq4.x, sq4.y, sq4.z, sq4.w };
#pragma unroll
        for (int r = 0; r < 4; ++r) {
            const float d0 = __fadd_rn(__fmaf_rn(-2.0f, acc0[r], sqa[r]), bias0);
            const float d1 = __fadd_rn(__fmaf_rn(-2.0f, acc1[r], sqa[r]), bias1);
            const unsigned key0 = (__float_as_uint(d0) & 0xFFFFF800u) | (unsigned)(mb + r);
            const unsigned key1 = (__float_as_uint(d1) & 0xFFFFF800u) | (unsigned)(mb + r);
            // two independent sorted-top-4 insert trees
            const unsigned oa0 = a0, oa1 = a1, oa2 = a2;
            a0 = umin2(key0, a0);
            a1 = med3u(key0, oa0, a1);
            a2 = med3u(key0, oa1, a2);
            a3 = med3u(key0, oa2, a3);
            const unsigned oc0 = c0, oc1 = c1, oc2 = c2;
            c0 = umin2(key1, c0);
            c1 = med3u(key1, oc0, c1);
            c2 = med3u(key1, oc1, c2);
            c3 = med3u(key1, oc2, c3);
        }
    }

    // store raw keys: plane p = quad*4+j, addr (p*BATCH+b)*NTOK + n
    const size_t plane = (size_t)BATCH * NTOK;
    unsigned* kp0 = keyws + ((size_t)(quad * 4) * BATCH + b) * NTOK + n0;
    unsigned* kp1 = keyws + ((size_t)(quad * 4) * BATCH + b) * NTOK + n1;
    kp0[0]         = a0;  kp1[0]         = c0;
    kp0[plane]     = a1;  kp1[plane]     = c1;
    kp0[2 * plane] = a2;  kp1[2 * plane] = c2;
    kp0[3 * plane] = a3;  kp1[3 * plane] = c3;
}

// Kernel 3: PARALLEL rescore + merge + conv (R22, proven). 4 threads per n:
// psub rescores planes psub*4..+3, stable lexicographic top-3; 4 partial lists
// merged in LDS ((d,idx) total order); conv split over o = psub*8..+7.
__global__ void __launch_bounds__(256) rescore_conv_kernel(
    const float* __restrict__ xTf, const float* __restrict__ sqf,
    const unsigned* __restrict__ keyws, const float* __restrict__ W,
    const float* __restrict__ bias, float* __restrict__ out)
{
    __shared__ float lds_d[4][3][64];
    __shared__ int   lds_i[4][3][64];
    __shared__ int   lds_idx[3][64];

    const int tid     = threadIdx.x;
    const int psub    = tid >> 6;       // 0..3: plane group
    const int n_local = tid & 63;

    // decode swizzled block coords: wg = (b%8) + 8*((b/8)*32 + nc), 1024 blocks
    const int wg   = blockIdx.x;        // 0..1023
    const int b_lo = wg & 7;
    const int t2   = wg >> 3;           // 0..127
    const int b_hi = t2 >> 5;           // 0..3
    const int nc   = t2 & 31;           // 0..31 (64-n chunk)
    const int b    = b_lo + (b_hi << 3);
    const int n    = nc * 64 + n_local;

    const float* sqb = sqf + (size_t)b * NTOK;
    const float* xb  = xTf + (size_t)b * NTOK * C_IN;

    float xn[C_IN];
    {
        const float4* src = (const float4*)(xb + (size_t)n * C_IN);
#pragma unroll
        for (int j = 0; j < 4; ++j) {
            const float4 tq = src[j];
            xn[4*j+0] = tq.x; xn[4*j+1] = tq.y; xn[4*j+2] = tq.z; xn[4*j+3] = tq.w;
        }
    }
    const float sqn = sqb[n];

    float D0 = FLT_MAX, D1 = FLT_MAX, D2 = FLT_MAX;
    int   I0 = INT_MAX, I1 = INT_MAX, I2 = INT_MAX;
    const size_t plane = (size_t)BATCH * NTOK;
    const size_t kbase = (size_t)b * NTOK + n + (size_t)(psub * 4) * plane;

#pragma unroll
    for (int p = 0; p < 4; ++p) {
        const unsigned key = keyws[kbase + (size_t)p * plane];
        const int mi = (int)(key & 2047u);

        // exact (reference-rounded) distance
        const float4* xm4 = (const float4*)(xb + (size_t)mi * C_IN);
        const float4 q0 = xm4[0], q1 = xm4[1], q2 = xm4[2], q3 = xm4[3];
        float g = 0.0f;
        g = __fmaf_rn(xn[0],  q0.x, g); g = __fmaf_rn(xn[1],  q0.y, g);
        g = __fmaf_rn(xn[2],  q0.z, g); g = __fmaf_rn(xn[3],  q0.w, g);
        g = __fmaf_rn(xn[4],  q1.x, g); g = __fmaf_rn(xn[5],  q1.y, g);
        g = __fmaf_rn(xn[6],  q1.z, g); g = __fmaf_rn(xn[7],  q1.w, g);
        g = __fmaf_rn(xn[8],  q2.x, g); g = __fmaf_rn(xn[9],  q2.y, g);
        g = __fmaf_rn(xn[10], q2.z, g); g = __fmaf_rn(xn[11], q2.w, g);
        g = __fmaf_rn(xn[12], q3.x, g); g = __fmaf_rn(xn[13], q3.y, g);
        g = __fmaf_rn(xn[14], q3.z, g); g = __fmaf_rn(xn[15], q3.w, g);
        const float d = __fadd_rn(__fmaf_rn(-2.0f, g, sqn), sqb[mi]);

        // stable lexicographic insert (d, mi)
        const bool c0 = (d < D0) || (d == D0 && mi < I0);
        const bool c1 = (d < D1) || (d == D1 && mi < I1);
        const bool c2 = (d < D2) || (d == D2 && mi < I2);
        const float oD0 = D0, oD1 = D1;
        const int   oI0 = I0, oI1 = I1;
        D0 = c0 ? d : D0;               I0 = c0 ? mi : I0;
        D1 = c0 ? oD0 : (c1 ? d : D1);  I1 = c0 ? oI0 : (c1 ? mi : I1);
        D2 = c1 ? oD1 : (c2 ? d : D2);  I2 = c1 ? oI1 : (c2 ? mi : I2);
    }

    // publish partial top-3
    lds_d[psub][0][n_local] = D0;  lds_i[psub][0][n_local] = I0;
    lds_d[psub][1][n_local] = D1;  lds_i[psub][1][n_local] = I1;
    lds_d[psub][2][n_local] = D2;  lds_i[psub][2][n_local] = I2;
    __syncthreads();

    // psub 0 merges the other 3 partial lists ((d,idx) total order)
    if (psub == 0) {
#pragma unroll
        for (int s = 1; s < 4; ++s) {
#pragma unroll
            for (int k = 0; k < KNN; ++k) {
                const float d  = lds_d[s][k][n_local];
                const int   mi = lds_i[s][k][n_local];
                const bool c0 = (d < D0) || (d == D0 && mi < I0);
                const bool c1 = (d < D1) || (d == D1 && mi < I1);
                const bool c2 = (d < D2) || (d == D2 && mi < I2);
                const float oD0 = D0, oD1 = D1;
                const int   oI0 = I0, oI1 = I1;
                D0 = c0 ? d : D0;               I0 = c0 ? mi : I0;
                D1 = c0 ? oD0 : (c1 ? d : D1);  I1 = c0 ? oI0 : (c1 ? mi : I1);
                D2 = c1 ? oD1 : (c2 ? d : D2);  I2 = c1 ? oI1 : (c2 ? mi : I2);
            }
        }
        lds_idx[0][n_local] = I0;
        lds_idx[1][n_local] = I1;
        lds_idx[2][n_local] = I2;
    }
    __syncthreads();

    // all threads: gather 3 neighbor columns, conv over o = psub*8..+7
    const int idx[KNN] = { lds_idx[0][n_local], lds_idx[1][n_local], lds_idx[2][n_local] };
    float xg[KNN][C_IN];
#pragma unroll
    for (int k = 0; k < KNN; ++k) {
        const float4* src = (const float4*)(xb + (size_t)idx[k] * C_IN);
#pragma unroll
        for (int j = 0; j < 4; ++j) {
            const float4 t = src[j];
            xg[k][4*j+0] = t.x; xg[k][4*j+1] = t.y;
            xg[k][4*j+2] = t.z; xg[k][4*j+3] = t.w;
        }
    }

#pragma unroll
    for (int oo = 0; oo < C_OUT / 4; ++oo) {
        const int o = psub * (C_OUT / 4) + oo;
        float acc = bias[o];
#pragma unroll
        for (int c = 0; c < C_IN; ++c) {
#pragma unroll
            for (int k = 0; k < KNN; ++k)
                acc = __fmaf_rn(W[(o * C_IN + c) * KNN + k], xg[k][c], acc);
        }
        out[((size_t)b * C_OUT + o) * NTOK + n] = acc;
    }
}

extern "C" void kernel_launch(void* const* d_in, const int* in_sizes, int n_in,
                              void* d_out, int out_size, void* d_ws, size_t ws_size,
                              hipStream_t stream) {
    const float* x    = (const float*)d_in[0];
    const float* W    = (const float*)d_in[1];
    const float* bias = (const float*)d_in[2];
    float* out = (float*)d_out;

    char* ws = (char*)d_ws;
    const size_t BN = (size_t)BATCH * NTOK;
    uint4*    Am    = (uint4*)ws;                           // 4 MB
    float*    sqf   = (float*)(ws + BN * 64);               // 256 KB
    float*    xTf   = (float*)(ws + BN * 68);               // 4 MB
    unsigned* keyws = (unsigned*)(ws + BN * 68 + BN * 64);  // 16 planes = 4 MB

    dim3 grid1(NTOK / 256, BATCH);
    prep_kernel<<<grid1, 256, 0, stream>>>(x, xTf, sqf, Am);

    // 512 blocks x 256 thr, 1-D, XCD-swizzled (2 n-tiles per wave)
    knn_scan_kernel<<<dim3(BATCH * (NTOK / (16 * WPB * 2))), 256, 0, stream>>>(Am, sqf, keyws);

    // 1024 blocks, 1-D, XCD-swizzled (4 threads per n, 4 planes each)
    rescore_conv_kernel<<<dim3(BATCH * (NTOK / 64)), 256, 0, stream>>>(xTf, sqf, keyws, W, bias, out);
}

// Round 24
// 73.579 us; speedup vs baseline: 1.0436x; 1.0436x over previous
//
#include <hip/hip_runtime.h>
#include <float.h>
#include <limits.h>

#define BATCH 32
#define C_IN 16
#define C_OUT 32
#define NTOK 2048
#define KNN 3
#define WPB 4                 // waves per scan block
#define NPLANE 16             // key planes: quad*4 + j

using f32x4v = __attribute__((ext_vector_type(4))) float;
using bf16x8 = __attribute__((ext_vector_type(8))) short;

__device__ __forceinline__ unsigned short f2bf(float f) {
    unsigned u = __float_as_uint(f);
    unsigned r = u + 0x7fffu + ((u >> 16) & 1u);   // RNE
    return (unsigned short)(r >> 16);
}
__device__ __forceinline__ float bf2f(unsigned short h) {
    return __uint_as_float(((unsigned)h) << 16);
}
__device__ __forceinline__ unsigned umin2(unsigned a, unsigned b) { return a < b ? a : b; }
__device__ __forceinline__ unsigned med3u(unsigned a, unsigned b, unsigned c) {
    unsigned d;
    asm("v_med3_u32 %0, %1, %2, %3" : "=v"(d) : "v"(a), "v"(b), "v"(c));
    return d;
}

// Kernel 1: per (b,n): sq (exact ref recipe), xTf fp32 column, Am bf16 hi/lo split.
// Am layout: FRAGMENT-TILE-INTERLEAVED (R13): uint4 index nt*64 + q*16 + col holds
// k-chunk q (0,1 = hi; 2,3 = lo) of row nt*16+col. 128-thr blocks, 512 blocks
// (2 blocks/CU) to latency-hide the 16 stride-8KB loads per thread.
__global__ void __launch_bounds__(128) prep_kernel(
    const float* __restrict__ x, float* __restrict__ xTf,
    float* __restrict__ sqf, uint4* __restrict__ Am)
{
    const int n = blockIdx.x * 128 + threadIdx.x;
    const int b = blockIdx.y;
    const float* xb = x + (size_t)b * C_IN * NTOK;

    float v[C_IN];
#pragma unroll
    for (int c = 0; c < C_IN; ++c) v[c] = xb[(size_t)c * NTOK + n];

    float acc = 0.0f;
#pragma unroll
    for (int c = 0; c < C_IN; ++c) acc = __fadd_rn(acc, __fmul_rn(v[c], v[c]));
    sqf[(size_t)b * NTOK + n] = acc;

    float4* dst = (float4*)(xTf + ((size_t)b * NTOK + n) * C_IN);
#pragma unroll
    for (int j = 0; j < 4; ++j)
        dst[j] = make_float4(v[4*j+0], v[4*j+1], v[4*j+2], v[4*j+3]);

    unsigned hw[8], lw[8];
#pragma unroll
    for (int j = 0; j < 8; ++j) {
        const unsigned short h0 = f2bf(v[2*j]),   h1 = f2bf(v[2*j+1]);
        const unsigned short l0 = f2bf(v[2*j]   - bf2f(h0));
        const unsigned short l1 = f2bf(v[2*j+1] - bf2f(h1));
        hw[j] = (unsigned)h0 | ((unsigned)h1 << 16);
        lw[j] = (unsigned)l0 | ((unsigned)l1 << 16);
    }
    uint4* amb = Am + (size_t)b * NTOK * 4;
    const int nt  = n >> 4;
    const int col = n & 15;
    amb[nt*64 + 0*16 + col] = make_uint4(hw[0], hw[1], hw[2], hw[3]);  // hi chunk0
    amb[nt*64 + 1*16 + col] = make_uint4(hw[4], hw[5], hw[6], hw[7]);  // hi chunk1
    amb[nt*64 + 2*16 + col] = make_uint4(lw[0], lw[1], lw[2], lw[3]);  // lo chunk0
    amb[nt*64 + 3*16 + col] = make_uint4(lw[4], lw[5], lw[6], lw[7]);  // lo chunk1
}

// Kernel 2: LEAN scan, ZH=1 (R22, proven 47.5 us). Each wave scans all 2048 m
// for its 16 n; per-lane top-4 over a disjoint 512-m subset; 4 coalesced raw-key
// stores. VGPR 24, no LDS.
__global__ void __launch_bounds__(256) knn_scan_kernel(
    const uint4* __restrict__ Am, const float* __restrict__ sqf,
    unsigned* __restrict__ keyws)
{
    const int tid  = threadIdx.x;
    const int w    = tid >> 6;
    const int l    = tid & 63;
    const int col  = l & 15;
    const int quad = l >> 4;

    // decode swizzled block coords: wgid = (b%8) + 8*((b/8)*32 + ntb)
    const int wg   = blockIdx.x;        // 0..1023
    const int b_lo = wg & 7;
    const int t2   = wg >> 3;           // 0..127
    const int b_hi = t2 >> 5;           // 0..3
    const int ntb  = t2 & 31;           // 0..31
    const int b    = b_lo + (b_hi << 3);
    const int nt   = ntb * WPB + w;

    const int n  = nt * 16 + col;

    const uint4* amb = Am + (size_t)b * NTOK * 4;
    const float* sqb = sqf + (size_t)b * NTOK;

    // B-frags from interleaved layout (R13)
    const uint4 bh4 = amb[(size_t)nt*64 + ((quad & 1) * 16) + col];
    const uint4 bl4 = amb[(size_t)nt*64 + ((2 + (quad & 1)) * 16) + col];
    const bf16x8 Bhi = *(const bf16x8*)&bh4;
    const bf16x8 Blo = *(const bf16x8*)&bl4;

    // ranking bias: biased key strictly positive -> uint compare monotone (R14)
    const float bias = sqb[n] + 4.0f;

    unsigned k0 = ~0u, k1 = ~0u, k2 = ~0u, k3 = ~0u;
    const int moff = quad * 4;

#pragma unroll 2
    for (int t = 0; t < NTOK / 16; ++t) {
        // A-frag: contiguous 1 KB tile, lane l reads element l (coalesced)
        const uint4 af4 = amb[(size_t)t * 64 + l];
        const bf16x8 Af = *(const bf16x8*)&af4;
        const float4 sq4 = *(const float4*)(sqb + t * 16 + moff);

        f32x4v acc = {0.0f, 0.0f, 0.0f, 0.0f};
        acc = __builtin_amdgcn_mfma_f32_16x16x32_bf16(Af, Bhi, acc, 0, 0, 0);
        acc = __builtin_amdgcn_mfma_f32_16x16x32_bf16(Af, Blo, acc, 0, 0, 0);

        const int mb = t * 16 + moff;
        const float sqa[4] = { sq4.x, sq4.y, sq4.z, sq4.w };
#pragma unroll
        for (int r = 0; r < 4; ++r) {
            // biased ranking distance (> 0): fma + add
            const float d = __fadd_rn(__fmaf_rn(-2.0f, acc[r], sqa[r]), bias);
            // key: truncate low 11 mantissa bits, pack GLOBAL m (fits: NTOK=2048)
            const unsigned key = (__float_as_uint(d) & 0xFFFFF800u) | (unsigned)(mb + r);
            // sorted-top-4 insert: min + 3x med3
            const unsigned ok0 = k0, ok1 = k1, ok2 = k2;
            k0 = umin2(key, k0);
            k1 = med3u(key, ok0, k1);
            k2 = med3u(key, ok1, k2);
            k3 = med3u(key, ok2, k3);
        }
    }

    // store 4 raw keys: plane p = quad*4+j, addr (p*BATCH+b)*NTOK + n
    const size_t plane = (size_t)BATCH * NTOK;
    unsigned* kp = keyws + ((size_t)(quad * 4) * BATCH + b) * NTOK + n;
    kp[0]         = k0;
    kp[plane]     = k1;
    kp[2 * plane] = k2;
    kp[3 * plane] = k3;
}

// Kernel 3: PARALLEL rescore + merge + conv (R22, proven). 4 threads per n:
// psub rescores planes psub*4..+3, stable lexicographic top-3; 4 partial lists
// merged in LDS ((d,idx) total order -> merge == full 16-candidate stable top-3
// == jax top_k of the full scan); conv split over o = psub*8..+7.
__global__ void __launch_bounds__(256) rescore_conv_kernel(
    const float* __restrict__ xTf, const float* __restrict__ sqf,
    const unsigned* __restrict__ keyws, const float* __restrict__ W,
    const float* __restrict__ bias, float* __restrict__ out)
{
    __shared__ float lds_d[4][3][64];
    __shared__ int   lds_i[4][3][64];
    __shared__ int   lds_idx[3][64];

    const int tid     = threadIdx.x;
    const int psub    = tid >> 6;       // 0..3: plane group
    const int n_local = tid & 63;

    // decode swizzled block coords: wg = (b%8) + 8*((b/8)*32 + nc), 1024 blocks
    const int wg   = blockIdx.x;        // 0..1023
    const int b_lo = wg & 7;
    const int t2   = wg >> 3;           // 0..127
    const int b_hi = t2 >> 5;           // 0..3
    const int nc   = t2 & 31;           // 0..31 (64-n chunk)
    const int b    = b_lo + (b_hi << 3);
    const int n    = nc * 64 + n_local;

    const float* sqb = sqf + (size_t)b * NTOK;
    const float* xb  = xTf + (size_t)b * NTOK * C_IN;

    float xn[C_IN];
    {
        const float4* src = (const float4*)(xb + (size_t)n * C_IN);
#pragma unroll
        for (int j = 0; j < 4; ++j) {
            const float4 tq = src[j];
            xn[4*j+0] = tq.x; xn[4*j+1] = tq.y; xn[4*j+2] = tq.z; xn[4*j+3] = tq.w;
        }
    }
    const float sqn = sqb[n];

    float D0 = FLT_MAX, D1 = FLT_MAX, D2 = FLT_MAX;
    int   I0 = INT_MAX, I1 = INT_MAX, I2 = INT_MAX;
    const size_t plane = (size_t)BATCH * NTOK;
    const size_t kbase = (size_t)b * NTOK + n + (size_t)(psub * 4) * plane;

#pragma unroll
    for (int p = 0; p < 4; ++p) {
        const unsigned key = keyws[kbase + (size_t)p * plane];
        const int mi = (int)(key & 2047u);

        // exact (reference-rounded) distance
        const float4* xm4 = (const float4*)(xb + (size_t)mi * C_IN);
        const float4 q0 = xm4[0], q1 = xm4[1], q2 = xm4[2], q3 = xm4[3];
        float g = 0.0f;
        g = __fmaf_rn(xn[0],  q0.x, g); g = __fmaf_rn(xn[1],  q0.y, g);
        g = __fmaf_rn(xn[2],  q0.z, g); g = __fmaf_rn(xn[3],  q0.w, g);
        g = __fmaf_rn(xn[4],  q1.x, g); g = __fmaf_rn(xn[5],  q1.y, g);
        g = __fmaf_rn(xn[6],  q1.z, g); g = __fmaf_rn(xn[7],  q1.w, g);
        g = __fmaf_rn(xn[8],  q2.x, g); g = __fmaf_rn(xn[9],  q2.y, g);
        g = __fmaf_rn(xn[10], q2.z, g); g = __fmaf_rn(xn[11], q2.w, g);
        g = __fmaf_rn(xn[12], q3.x, g); g = __fmaf_rn(xn[13], q3.y, g);
        g = __fmaf_rn(xn[14], q3.z, g); g = __fmaf_rn(xn[15], q3.w, g);
        const float d = __fadd_rn(__fmaf_rn(-2.0f, g, sqn), sqb[mi]);

        // stable lexicographic insert (d, mi)
        const bool c0 = (d < D0) || (d == D0 && mi < I0);
        const bool c1 = (d < D1) || (d == D1 && mi < I1);
        const bool c2 = (d < D2) || (d == D2 && mi < I2);
        const float oD0 = D0, oD1 = D1;
        const int   oI0 = I0, oI1 = I1;
        D0 = c0 ? d : D0;               I0 = c0 ? mi : I0;
        D1 = c0 ? oD0 : (c1 ? d : D1);  I1 = c0 ? oI0 : (c1 ? mi : I1);
        D2 = c1 ? oD1 : (c2 ? d : D2);  I2 = c1 ? oI1 : (c2 ? mi : I2);
    }

    // publish partial top-3
    lds_d[psub][0][n_local] = D0;  lds_i[psub][0][n_local] = I0;
    lds_d[psub][1][n_local] = D1;  lds_i[psub][1][n_local] = I1;
    lds_d[psub][2][n_local] = D2;  lds_i[psub][2][n_local] = I2;
    __syncthreads();

    // psub 0 merges the other 3 partial lists ((d,idx) total order)
    if (psub == 0) {
#pragma unroll
        for (int s = 1; s < 4; ++s) {
#pragma unroll
            for (int k = 0; k < KNN; ++k) {
                const float d  = lds_d[s][k][n_local];
                const int   mi = lds_i[s][k][n_local];
                const bool c0 = (d < D0) || (d == D0 && mi < I0);
                const bool c1 = (d < D1) || (d == D1 && mi < I1);
                const bool c2 = (d < D2) || (d == D2 && mi < I2);
                const float oD0 = D0, oD1 = D1;
                const int   oI0 = I0, oI1 = I1;
                D0 = c0 ? d : D0;               I0 = c0 ? mi : I0;
                D1 = c0 ? oD0 : (c1 ? d : D1);  I1 = c0 ? oI0 : (c1 ? mi : I1);
                D2 = c1 ? oD1 : (c2 ? d : D2);  I2 = c1 ? oI1 : (c2 ? mi : I2);
            }
        }
        lds_idx[0][n_local] = I0;
        lds_idx[1][n_local] = I1;
        lds_idx[2][n_local] = I2;
    }
    __syncthreads();

    // all threads: gather 3 neighbor columns, conv over o = psub*8..+7
    const int idx[KNN] = { lds_idx[0][n_local], lds_idx[1][n_local], lds_idx[2][n_local] };
    float xg[KNN][C_IN];
#pragma unroll
    for (int k = 0; k < KNN; ++k) {
        const float4* src = (const float4*)(xb + (size_t)idx[k] * C_IN);
#pragma unroll
        for (int j = 0; j < 4; ++j) {
            const float4 t = src[j];
            xg[k][4*j+0] = t.x; xg[k][4*j+1] = t.y;
            xg[k][4*j+2] = t.z; xg[k][4*j+3] = t.w;
        }
    }

#pragma unroll
    for (int oo = 0; oo < C_OUT / 4; ++oo) {
        const int o = psub * (C_OUT / 4) + oo;
        float acc = bias[o];
#pragma unroll
        for (int c = 0; c < C_IN; ++c) {
#pragma unroll
            for (int k = 0; k < KNN; ++k)
                acc = __fmaf_rn(W[(o * C_IN + c) * KNN + k], xg[k][c], acc);
        }
        out[((size_t)b * C_OUT + o) * NTOK + n] = acc;
    }
}

extern "C" void kernel_launch(void* const* d_in, const int* in_sizes, int n_in,
                              void* d_out, int out_size, void* d_ws, size_t ws_size,
                              hipStream_t stream) {
    const float* x    = (const float*)d_in[0];
    const float* W    = (const float*)d_in[1];
    const float* bias = (const float*)d_in[2];
    float* out = (float*)d_out;

    char* ws = (char*)d_ws;
    const size_t BN = (size_t)BATCH * NTOK;
    uint4*    Am    = (uint4*)ws;                           // 4 MB
    float*    sqf   = (float*)(ws + BN * 64);               // 256 KB
    float*    xTf   = (float*)(ws + BN * 68);               // 4 MB
    unsigned* keyws = (unsigned*)(ws + BN * 68 + BN * 64);  // 16 planes = 4 MB

    // 512 blocks x 128 thr (2 blocks/CU)
    dim3 grid1(NTOK / 128, BATCH);
    prep_kernel<<<grid1, 128, 0, stream>>>(x, xTf, sqf, Am);

    // 1024 blocks x 256 thr, 1-D, XCD-swizzled (ZH=1: full m-range per wave)
    knn_scan_kernel<<<dim3(BATCH * (NTOK / (16 * WPB))), 256, 0, stream>>>(Am, sqf, keyws);

    // 1024 blocks, 1-D, XCD-swizzled (4 threads per n, 4 planes each)
    rescore_conv_kernel<<<dim3(BATCH * (NTOK / 64)), 256, 0, stream>>>(xTf, sqf, keyws, W, bias, out);
}